// Round 9
// baseline (59.723 us; speedup 1.0000x reference)
//
#include <hip/hip_runtime.h>
#include <hip/hip_bf16.h>

// AlignmentLoss: loss = -(sum(tril(G,-1)*eq) / (sum(tril(eq,-1)) * ||tril(G,-1)||_F))
// with G = A A^T, A: 4096x1024 fp32, target: 4096 int32 (classes < 1000).
//
//   S1 = 0.5*(sum_c ||s_c||^2 - sum_i r_i),  r_i = ||a_i||^2   (exact fp32)
//   S2 = 0.5*(sum_c n_c^2 - N)
//   S3 = 0.5*(||M||_F^2 - sum_i r_i^2),  M = A^T A  (1024x1024, symmetric;
//        ||A A^T||_F = ||A^T A||_F via singular values)
//   loss = -S1 / (S2 * sqrt(S3))
//
// R9 (structural): gram moved to the SMALL side.  36 lower-triangle 128^2
// tiles of M, 8-way split-K (chunks of 512 rows) -> 288 blocks, 4.8 GFLOP
// (vs 17.7 for the NxN path).  Frobenius is nonlinear, so per-chunk partial
// C-tiles are materialized (18.9 MB slabs) and kred sums/squares them with
// the triangle weight (2 below diag / 1 on diag / 0 above; transpose-safe
// because M is symmetric).  Chunk-per-XCD swizzle: each XCD's chunk data is
// ~1 MB -> L2-resident.  ktrans (R1-verified) fuses per-row ||a_i||^2.

typedef __attribute__((ext_vector_type(8))) short short8;
typedef __attribute__((ext_vector_type(4))) float f32x4;

#define N_ROWS 4096
#define D_DIM  1024
#define N_CLS  1000
#define NCHUNK 8           // split-K chunks of 512 rows
#define NTIL   36          // 8x8 lower-triangle tiles of M
#define NKG    16          // 512 / BK, BK = 32

__device__ __forceinline__ unsigned short f2bf(float f) {
  unsigned u = __float_as_uint(f);
  u += 0x7fffu + ((u >> 16) & 1u);   // round-to-nearest-even
  return (unsigned short)(u >> 16);
}

__device__ __forceinline__ void gload16(const short* g, const char* l) {
  __builtin_amdgcn_global_load_lds(
      (const __attribute__((address_space(1))) unsigned*)g,
      (__attribute__((address_space(3))) unsigned*)(void*)l, 16, 0, 0);
}

// ---------------------------------------------------------------------------
// kprep: blocks 0..1023  = transpose A -> At bf16 [1024][4096] + row-norm
//                          partials rowsqp[16][4096] (per 64-dim slice)
//        blocks 1024..   = per-class sum-vector norm + count (exact fp32)
// ---------------------------------------------------------------------------
__global__ void __launch_bounds__(256) kprep(const float* __restrict__ A,
                                             const int* __restrict__ target,
                                             short* __restrict__ At,
                                             float* __restrict__ rowsqp,
                                             double* __restrict__ cssp,
                                             int* __restrict__ cntp) {
  const int tid = threadIdx.x, lane = tid & 63, w = tid >> 6;

  if (blockIdx.x < 1024) {
    // ---- transpose + convert + row-norm partials (R1-verified structure) ----
    __shared__ short tile[64 * 68];      // [d_local][i_local], pitch 68
    const int bx = blockIdx.x & 63, by = blockIdx.x >> 6;
    const int i0 = bx * 64, d0 = by * 64;
    const int c16 = tid & 15, rgrp = tid >> 4;
#pragma unroll
    for (int rr = 0; rr < 4; ++rr) {
      const int row = rgrp + rr * 16;    // i_local 0..63
      const float4 v = *(const float4*)(A + (size_t)(i0 + row) * D_DIM + d0 + c16 * 4);
      tile[(c16 * 4 + 0) * 68 + row] = (short)f2bf(v.x);
      tile[(c16 * 4 + 1) * 68 + row] = (short)f2bf(v.y);
      tile[(c16 * 4 + 2) * 68 + row] = (short)f2bf(v.z);
      tile[(c16 * 4 + 3) * 68 + row] = (short)f2bf(v.w);
      // fused row-norm partial over this 64-dim slice
      float s = v.x * v.x + v.y * v.y + v.z * v.z + v.w * v.w;
#pragma unroll
      for (int off = 1; off < 16; off <<= 1) s += __shfl_xor(s, off);
      if (c16 == 0) rowsqp[(by << 12) + i0 + row] = s;
    }
    __syncthreads();
    const int wrow = tid >> 2, wc = tid & 3;   // d_local, 16-short chunk
    short8 s0, s1;
#pragma unroll
    for (int q = 0; q < 8; ++q) {
      s0[q] = tile[wrow * 68 + wc * 16 + q];
      s1[q] = tile[wrow * 68 + wc * 16 + 8 + q];
    }
    short* dst = At + (size_t)(d0 + wrow) * N_ROWS + i0 + wc * 16;
    *(short8*)(dst)     = s0;
    *(short8*)(dst + 8) = s1;
  } else {
    // ---- per-class reduction ----
    __shared__ int list[N_ROWS];
    __shared__ int lcnt;
    __shared__ float wred[4];
    const int c = blockIdx.x - 1024;
    if (c >= N_CLS) return;
    if (tid == 0) lcnt = 0;
    __syncthreads();
    for (int j = tid; j < N_ROWS; j += 256)
      if (target[j] == c) { int p = atomicAdd(&lcnt, 1); list[p] = j; }
    __syncthreads();
    const int n = lcnt;
    float4 acc = make_float4(0.f, 0.f, 0.f, 0.f);
    for (int m = 0; m < n; ++m) {
      const float4 v = *(const float4*)(A + (size_t)list[m] * D_DIM + tid * 4);
      acc.x += v.x; acc.y += v.y; acc.z += v.z; acc.w += v.w;
    }
    float s = acc.x * acc.x + acc.y * acc.y + acc.z * acc.z + acc.w * acc.w;
#pragma unroll
    for (int off = 32; off; off >>= 1) s += __shfl_down(s, off);
    if (lane == 0) wred[w] = s;
    __syncthreads();
    if (tid == 0) {
      cssp[c] = (double)(wred[0] + wred[1] + wred[2] + wred[3]);
      cntp[c] = n;
    }
  }
}

// ---------------------------------------------------------------------------
// kgemm: M-chunk tiles.  block = (chunk c, triangle tile tt); computes the
// 128x128 tile of At[.,c-slice] * At[.,c-slice]^T (K=512) and stores the raw
// fp32 accumulators to slab (no reduction here).  R8 pipeline + swizzles.
// ---------------------------------------------------------------------------
__global__ void __launch_bounds__(256, 2) kgemm(const short* __restrict__ At,
                                                float* __restrict__ slab) {
  __shared__ __align__(16) short As[2][128 * 32];   // 2 x 8 KB
  __shared__ __align__(16) short Bs[2][128 * 32];   // 2 x 8 KB
  const int tid = threadIdx.x, lane = tid & 63, w = tid >> 6;

  // chunk-per-XCD swizzle: 288 = 8 chunks x 36 tiles
  const int c  = blockIdx.x & 7;
  const int tt = blockIdx.x >> 3;           // 0..35

  // decode lower-triangle pair: tt = bi*(bi+1)/2 + bj, bj <= bi  (bi,bj < 8)
  int bi = (int)((sqrtf(8.f * (float)tt + 1.f) - 1.f) * 0.5f);
  while ((bi + 1) * (bi + 2) / 2 <= tt) ++bi;
  while (bi * (bi + 1) / 2 > tt) --bi;
  const int bj = tt - bi * (bi + 1) / 2;

  const short* Pa = At + (size_t)(bi * 128) * N_ROWS + c * 512;
  const short* Pb = At + (size_t)(bj * 128) * N_ROWS + c * 512;

  f32x4 acc[4][4];
#pragma unroll
  for (int m = 0; m < 4; ++m)
#pragma unroll
    for (int n = 0; n < 4; ++n) acc[m][n] = (f32x4){0.f, 0.f, 0.f, 0.f};

  const int wr = w >> 1, wc = w & 1;             // wave tile: 64x64
  const int row16 = lane & 15, ck = lane >> 4;

  // staging: 256 thr x 16B x 2 issues per matrix = [128][32]-short buffer.
  // global chunk pre-swizzled (chunk ^= (row>>1)&3); LDS linear.
  const int sr = tid >> 2;
  const int scS = (tid & 3) ^ ((sr >> 1) & 3);
  const size_t g0 = (size_t)sr * N_ROWS + scS * 8;          // rows 0..63
  const size_t g1 = (size_t)(sr + 64) * N_ROWS + scS * 8;   // rows 64..127
  const int l0 = w * 1024;
  const int l1 = 4096 + w * 1024;

#define STAGE(buf, k0)                                                      \
  do {                                                                      \
    gload16(Pa + g0 + (k0), (const char*)As[buf] + l0);                     \
    gload16(Pa + g1 + (k0), (const char*)As[buf] + l1);                     \
    gload16(Pb + g0 + (k0), (const char*)Bs[buf] + l0);                     \
    gload16(Pb + g1 + (k0), (const char*)Bs[buf] + l1);                     \
  } while (0)

#define SWZ(R) (((R) * 32) + ((ck ^ (((R) >> 1) & 3)) * 8))

#define COMPUTE(buf)                                                        \
  do {                                                                      \
    short8 af[4], bf[4];                                                    \
    _Pragma("unroll")                                                       \
    for (int m = 0; m < 4; ++m)                                             \
      af[m] = *(const short8*)&As[buf][SWZ(wr * 64 + m * 16 + row16)];      \
    _Pragma("unroll")                                                       \
    for (int n = 0; n < 4; ++n)                                             \
      bf[n] = *(const short8*)&Bs[buf][SWZ(wc * 64 + n * 16 + row16)];      \
    _Pragma("unroll")                                                       \
    for (int m = 0; m < 4; ++m)                                             \
      _Pragma("unroll")                                                     \
      for (int n = 0; n < 4; ++n)                                           \
        acc[m][n] = __builtin_amdgcn_mfma_f32_16x16x32_bf16(af[m], bf[n],   \
                                                            acc[m][n], 0, 0, 0);\
  } while (0)

  STAGE(0, 0);
  int cur = 0;
#pragma unroll 1
  for (int t = 0; t < NKG - 1; ++t) {
    STAGE(cur ^ 1, (t + 1) * 32);
    asm volatile("s_waitcnt vmcnt(4)" ::: "memory");
    __builtin_amdgcn_sched_barrier(0);
    __builtin_amdgcn_s_barrier();
    __builtin_amdgcn_sched_barrier(0);
    COMPUTE(cur);
    asm volatile("s_waitcnt lgkmcnt(0)" ::: "memory");
    __builtin_amdgcn_sched_barrier(0);
    __builtin_amdgcn_s_barrier();
    __builtin_amdgcn_sched_barrier(0);
    cur ^= 1;
  }
  asm volatile("s_waitcnt vmcnt(0)" ::: "memory");
  __builtin_amdgcn_sched_barrier(0);
  __builtin_amdgcn_s_barrier();
  __builtin_amdgcn_sched_barrier(0);
  COMPUTE(cur);
#undef STAGE
#undef COMPUTE
#undef SWZ

  // store raw accumulators: slab[(c*36+tt)][frag 0..15][tid] as f32x4
  f32x4* sp = (f32x4*)slab + ((size_t)(c * NTIL + tt) * 16) * 256 + tid;
#pragma unroll
  for (int m = 0; m < 4; ++m)
#pragma unroll
    for (int n = 0; n < 4; ++n)
      sp[(size_t)(m * 4 + n) * 256] = acc[m][n];
}

// ---------------------------------------------------------------------------
// kred: per triangle tile, sum the 8 chunk slabs, apply triangle weight
// (2 strictly-below-diag / 1 diag / 0 above), square, reduce -> frobp2[tt].
// Grid NTIL=36 x 256 thr.
// ---------------------------------------------------------------------------
__global__ void __launch_bounds__(256) kred(const float* __restrict__ slab,
                                            double* __restrict__ frobp2) {
  __shared__ double wred[4];
  const int tid = threadIdx.x, lane = tid & 63, w = tid >> 6;
  const int tt = blockIdx.x;

  int bi = (int)((sqrtf(8.f * (float)tt + 1.f) - 1.f) * 0.5f);
  while ((bi + 1) * (bi + 2) / 2 <= tt) ++bi;
  while (bi * (bi + 1) / 2 > tt) --bi;
  const int bj = tt - bi * (bi + 1) / 2;
  const bool diag = (bi == bj);

  const int wr = w >> 1, wc = w & 1;
  const int rbase = (lane >> 4) * 4, cbase = lane & 15;
  const f32x4* sb = (const f32x4*)slab;

  float fs = 0.f;
#pragma unroll
  for (int f = 0; f < 16; ++f) {
    f32x4 v = (f32x4){0.f, 0.f, 0.f, 0.f};
#pragma unroll
    for (int c = 0; c < NCHUNK; ++c)
      v += sb[((size_t)(c * NTIL + tt) * 16 + f) * 256 + tid];
    const int m = f >> 2, n = f & 3;
    if (!diag) {
      fs += 2.f * (v[0] * v[0] + v[1] * v[1] + v[2] * v[2] + v[3] * v[3]);
    } else {
      const int cl = wc * 64 + n * 16 + cbase;
#pragma unroll
      for (int q = 0; q < 4; ++q) {
        const int rl = wr * 64 + m * 16 + rbase + q;
        const float wgt = (rl > cl) ? 2.f : ((rl == cl) ? 1.f : 0.f);
        fs += wgt * v[q] * v[q];
      }
    }
  }
#pragma unroll
  for (int off = 32; off; off >>= 1) fs += __shfl_down(fs, off);
  if (lane == 0) wred[w] = (double)fs;
  __syncthreads();
  if (tid == 0)
    frobp2[tt] = wred[0] + wred[1] + wred[2] + wred[3];
}

// ---------------------------------------------------------------------------
// kfinal: fp64 reduce + scalar math.
// ---------------------------------------------------------------------------
__global__ void __launch_bounds__(256) kfinal(const float* __restrict__ rowsqp,
                                              const double* __restrict__ cssp,
                                              const int* __restrict__ cntp,
                                              const double* __restrict__ frobp2,
                                              float* __restrict__ out) {
  __shared__ double red[256];
  const int tid = threadIdx.x;
  double lsum = 0.0, lsq = 0.0, lcss = 0.0, lcnn = 0.0, lfr = 0.0;
  for (int i = tid; i < N_ROWS; i += 256) {
    float r = 0.f;
#pragma unroll
    for (int b = 0; b < 16; ++b) r += rowsqp[(b << 12) + i];
    lsum += (double)r;
    lsq  += (double)r * (double)r;
  }
  for (int c = tid; c < N_CLS; c += 256) {
    lcss += cssp[c];
    const double nc = (double)cntp[c];
    lcnn += nc * nc;
  }
  if (tid < NTIL) lfr = frobp2[tid];

  double vals[5] = {lsum, lsq, lcss, lcnn, lfr};
  double res[5];
  for (int v = 0; v < 5; ++v) {
    red[tid] = vals[v];
    __syncthreads();
    for (int s = 128; s; s >>= 1) {
      if (tid < s) red[tid] += red[tid + s];
      __syncthreads();
    }
    res[v] = red[0];
    __syncthreads();
  }
  if (tid == 0) {
    const double sumr = res[0], sumq = res[1], css = res[2], cnn = res[3], F = res[4];
    const double S1 = 0.5 * (css - sumr);
    const double S2 = 0.5 * (cnn - (double)N_ROWS);
    const double S3 = 0.5 * (F - sumq);
    out[0] = (float)(-(S1 / (S2 * sqrt(S3))));
  }
}

extern "C" void kernel_launch(void* const* d_in, const int* in_sizes, int n_in,
                              void* d_out, int out_size, void* d_ws, size_t ws_size,
                              hipStream_t stream) {
  const float* A = (const float*)d_in[0];
  const int* target = (const int*)d_in[1];
  float* out = (float*)d_out;

  char* ws = (char*)d_ws;
  short*  At     = (short*)ws;                       // 8,388,608 B
  float*  slab   = (float*)(ws + 8388608);           // 18,874,368 B
  float*  rowsqp = (float*)(ws + 27262976);          // 262,144 B (16x4096 f32)
  double* cssp   = (double*)(ws + 27525120);         // 8,000 B (pad 8192)
  int*    cntp   = (int*)   (ws + 27533312);         // 4,000 B (pad 4096)
  double* frobp2 = (double*)(ws + 27537408);         // 288 B

  kprep<<<1024 + N_CLS, 256, 0, stream>>>(A, target, At, rowsqp, cssp, cntp);
  kgemm<<<NCHUNK * NTIL, 256, 0, stream>>>(At, slab);
  kred<<<NTIL, 256, 0, stream>>>(slab, frobp2);
  kfinal<<<1, 256, 0, stream>>>(rowsqp, cssp, cntp, frobp2, out);
}

// Round 10
// 47.731 us; speedup vs baseline: 1.2512x; 1.2512x over previous
//
#include <hip/hip_runtime.h>
#include <hip/hip_bf16.h>

// AlignmentLoss: loss = -(sum(tril(G,-1)*eq) / (sum(tril(eq,-1)) * ||tril(G,-1)||_F))
// with G = A A^T, A: 4096x1024 fp32, target: 4096 int32 (classes < 1000).
//
//   S1 = 0.5*(sum_c ||s_c||^2 - sum_i ||a_i||^2)   (exact fp32/fp64 path)
//   S2 = 0.5*(sum_c n_c^2 - N)
//   S3 = sum_{i>j} g_ij^2  -- lower-triangle 128x128 tiles of G = A A^T,
//        bf16 MFMA, K=1024, fused masked Frobenius.
//   loss = -S1 / (S2 * sqrt(S3))
//
// R10 (isolated vs R7-best; R9 small-side path reverted): kfrob prefetch
// depth 1 -> 2.  Triple-buffered LDS (48 KB), STAGE(t+2) issued each iter,
// main-loop wait = vmcnt(8) (T4: N = 4 loads/tile x 2 tiles in flight), so
// every tile's loads get ~2 phases (>600 cy) to land instead of ~300 cy.
// This attacks the one invariant across the five neutral variants R3-R8:
// per-K-step exposed global latency.  Also launch_bounds(256,3): 3 blocks/CU
// -> all 528 blocks co-resident (no 16-block tail).

typedef __attribute__((ext_vector_type(8))) short short8;
typedef __attribute__((ext_vector_type(4))) float f32x4;

#define N_ROWS 4096
#define D_DIM  1024
#define N_CLS  1000
#define NBLK   528         // 32*(32+1)/2 lower-triangle 128^2 tiles
#define NK     32          // 1024 / BK,  BK = 32

__device__ __forceinline__ unsigned short f2bf(float f) {
  unsigned u = __float_as_uint(f);
  u += 0x7fffu + ((u >> 16) & 1u);   // round-to-nearest-even
  return (unsigned short)(u >> 16);
}

__device__ __forceinline__ void gload16(const short* g, const char* l) {
  __builtin_amdgcn_global_load_lds(
      (const __attribute__((address_space(1))) unsigned*)g,
      (__attribute__((address_space(3))) unsigned*)(void*)l, 16, 0, 0);
}

// ---------------------------------------------------------------------------
// kprep: blocks 0..511  = convert A->bf16 + row-norm partials
//        blocks 512..   = per-class sum-vector norm + count
// ---------------------------------------------------------------------------
__global__ void __launch_bounds__(256) kprep(const float* __restrict__ A,
                                             const int* __restrict__ target,
                                             short* __restrict__ Ab,
                                             double* __restrict__ rowp,
                                             double* __restrict__ cssp,
                                             int* __restrict__ cntp) {
  const int tid = threadIdx.x, lane = tid & 63, w = tid >> 6;

  if (blockIdx.x < 512) {
    __shared__ double wr2[4];
    const int row0 = blockIdx.x * 8;
    double ls = 0.0;
#pragma unroll
    for (int rr = 0; rr < 2; ++rr) {
      const int i = row0 + w * 2 + rr;
      const float4* src = (const float4*)(A + (size_t)i * D_DIM);
      short4* dst = (short4*)(Ab + (size_t)i * D_DIM);
      float s = 0.f;
#pragma unroll
      for (int c = 0; c < 4; ++c) {
        const float4 v = src[lane + c * 64];
        s += v.x * v.x + v.y * v.y + v.z * v.z + v.w * v.w;
        short4 o;
        o.x = (short)f2bf(v.x); o.y = (short)f2bf(v.y);
        o.z = (short)f2bf(v.z); o.w = (short)f2bf(v.w);
        dst[lane + c * 64] = o;
      }
#pragma unroll
      for (int off = 32; off; off >>= 1) s += __shfl_down(s, off);
      if (lane == 0) ls += (double)s;
    }
    if (lane == 0) wr2[w] = ls;
    __syncthreads();
    if (tid == 0) rowp[blockIdx.x] = wr2[0] + wr2[1] + wr2[2] + wr2[3];
  } else {
    __shared__ int list[N_ROWS];
    __shared__ int lcnt;
    __shared__ float wred[4];
    const int c = blockIdx.x - 512;
    if (c >= N_CLS) return;
    if (tid == 0) lcnt = 0;
    __syncthreads();
    for (int j = tid; j < N_ROWS; j += 256)
      if (target[j] == c) { int p = atomicAdd(&lcnt, 1); list[p] = j; }
    __syncthreads();
    const int n = lcnt;
    float4 acc = make_float4(0.f, 0.f, 0.f, 0.f);
    for (int m = 0; m < n; ++m) {
      const float4 v = *(const float4*)(A + (size_t)list[m] * D_DIM + tid * 4);
      acc.x += v.x; acc.y += v.y; acc.z += v.z; acc.w += v.w;
    }
    float s = acc.x * acc.x + acc.y * acc.y + acc.z * acc.z + acc.w * acc.w;
#pragma unroll
    for (int off = 32; off; off >>= 1) s += __shfl_down(s, off);
    if (lane == 0) wred[w] = s;
    __syncthreads();
    if (tid == 0) {
      cssp[c] = (double)(wred[0] + wred[1] + wred[2] + wred[3]);
      cntp[c] = n;
    }
  }
}

// ---------------------------------------------------------------------------
// kfrob: lower-triangle 128x128 tiles of G = Ab*Ab^T, bf16 MFMA, 4 waves
// (2x2, 64x64 per wave), TRIPLE-buffered LDS with depth-2 prefetch and
// counted vmcnt(8), bank-swizzled, fused masked Frobenius.
// Grid NBLK=528 x 256 threads, 3 blocks/CU.
// ---------------------------------------------------------------------------
__global__ void __launch_bounds__(256, 3) kfrob(const short* __restrict__ Ab,
                                                double* __restrict__ frobp) {
  __shared__ __align__(16) short As[3][128 * 32];   // 3 x 8 KB
  __shared__ __align__(16) short Bs[3][128 * 32];   // 3 x 8 KB
  __shared__ double wred[4];
  const int tid = threadIdx.x, lane = tid & 63, w = tid >> 6;

  // XCD-aware swizzle: 528 = 8 * 66; XCD x gets contiguous triangle chunk.
  const int b = (blockIdx.x & 7) * 66 + (blockIdx.x >> 3);

  // decode lower-triangle pair: b = bi*(bi+1)/2 + bj, bj <= bi
  int bi = (int)((sqrtf(8.f * (float)b + 1.f) - 1.f) * 0.5f);
  while ((bi + 1) * (bi + 2) / 2 <= b) ++bi;
  while (bi * (bi + 1) / 2 > b) --bi;
  const int bj = b - bi * (bi + 1) / 2;
  const bool diag = (bi == bj);

  const short* Pa = Ab + (size_t)(bi * 128) * D_DIM;
  const short* Pb = Ab + (size_t)(bj * 128) * D_DIM;

  f32x4 acc[4][4];
#pragma unroll
  for (int m = 0; m < 4; ++m)
#pragma unroll
    for (int n = 0; n < 4; ++n) acc[m][n] = (f32x4){0.f, 0.f, 0.f, 0.f};

  const int wr = w >> 1, wc = w & 1;             // wave tile: 64x64
  const int row16 = lane & 15, ck = lane >> 4;

  // staging: 256 thr x 16B x 2 issues per matrix fills one [128][32] buffer.
  // global chunk pre-swizzled (chunk ^= (row>>1)&3); LDS linear (rule #21).
  const int sr = tid >> 2;
  const int scS = (tid & 3) ^ ((sr >> 1) & 3);
  const size_t g0 = (size_t)sr * D_DIM + scS * 8;          // rows 0..63
  const size_t g1 = (size_t)(sr + 64) * D_DIM + scS * 8;   // rows 64..127
  const int l0 = w * 1024;
  const int l1 = 4096 + w * 1024;

#define STAGE(buf, k0)                                                      \
  do {                                                                      \
    gload16(Pa + g0 + (k0), (const char*)As[buf] + l0);                     \
    gload16(Pa + g1 + (k0), (const char*)As[buf] + l1);                     \
    gload16(Pb + g0 + (k0), (const char*)Bs[buf] + l0);                     \
    gload16(Pb + g1 + (k0), (const char*)Bs[buf] + l1);                     \
  } while (0)

#define SWZ(R) (((R) * 32) + ((ck ^ (((R) >> 1) & 3)) * 8))

#define COMPUTE(buf)                                                        \
  do {                                                                      \
    short8 af[4], bf[4];                                                    \
    _Pragma("unroll")                                                       \
    for (int m = 0; m < 4; ++m)                                             \
      af[m] = *(const short8*)&As[buf][SWZ(wr * 64 + m * 16 + row16)];      \
    _Pragma("unroll")                                                       \
    for (int n = 0; n < 4; ++n)                                             \
      bf[n] = *(const short8*)&Bs[buf][SWZ(wc * 64 + n * 16 + row16)];      \
    _Pragma("unroll")                                                       \
    for (int m = 0; m < 4; ++m)                                             \
      _Pragma("unroll")                                                     \
      for (int n = 0; n < 4; ++n)                                           \
        acc[m][n] = __builtin_amdgcn_mfma_f32_16x16x32_bf16(af[m], bf[n],   \
                                                            acc[m][n], 0, 0, 0);\
  } while (0)

  // prologue: tiles 0 and 1 in flight (depth 2)
  STAGE(0, 0);
  STAGE(1, 32);
  int cur = 0, nxt = 2;
#pragma unroll 1
  for (int t = 0; t < NK - 2; ++t) {
    STAGE(nxt, (t + 2) * 32);        // issue tile t+2 (4 loads/thread)
    asm volatile("s_waitcnt vmcnt(8)" ::: "memory");   // tile t resident
    __builtin_amdgcn_sched_barrier(0);
    __builtin_amdgcn_s_barrier();
    __builtin_amdgcn_sched_barrier(0);
    COMPUTE(cur);
    asm volatile("s_waitcnt lgkmcnt(0)" ::: "memory"); // ds_reads retired
    __builtin_amdgcn_sched_barrier(0);
    __builtin_amdgcn_s_barrier();    // slot cur free for overwrite
    __builtin_amdgcn_sched_barrier(0);
    cur = (cur == 2) ? 0 : cur + 1;
    nxt = (nxt == 2) ? 0 : nxt + 1;
  }
  // t = NK-2: no stage; tiles {NK-2, NK-1} outstanding (8 loads)
  asm volatile("s_waitcnt vmcnt(4)" ::: "memory");
  __builtin_amdgcn_sched_barrier(0);
  __builtin_amdgcn_s_barrier();
  __builtin_amdgcn_sched_barrier(0);
  COMPUTE(cur);
  asm volatile("s_waitcnt lgkmcnt(0)" ::: "memory");
  __builtin_amdgcn_sched_barrier(0);
  __builtin_amdgcn_s_barrier();
  __builtin_amdgcn_sched_barrier(0);
  cur = (cur == 2) ? 0 : cur + 1;
  // t = NK-1: last tile
  asm volatile("s_waitcnt vmcnt(0)" ::: "memory");
  __builtin_amdgcn_sched_barrier(0);
  __builtin_amdgcn_s_barrier();
  __builtin_amdgcn_sched_barrier(0);
  COMPUTE(cur);
#undef STAGE
#undef COMPUTE
#undef SWZ

  float fs = 0.f;
  if (!diag) {
#pragma unroll
    for (int m = 0; m < 4; ++m)
#pragma unroll
      for (int n = 0; n < 4; ++n)
#pragma unroll
        for (int q = 0; q < 4; ++q) fs += acc[m][n][q] * acc[m][n][q];
  } else {
    const int rbase = (lane >> 4) * 4, cbase = lane & 15;
#pragma unroll
    for (int m = 0; m < 4; ++m)
#pragma unroll
      for (int n = 0; n < 4; ++n)
#pragma unroll
        for (int q = 0; q < 4; ++q) {
          const int rl = wr * 64 + m * 16 + rbase + q;
          const int cl = wc * 64 + n * 16 + cbase;
          if (rl > cl) fs += acc[m][n][q] * acc[m][n][q];
        }
  }
#pragma unroll
  for (int off = 32; off; off >>= 1) fs += __shfl_down(fs, off);
  if (lane == 0) wred[w] = (double)fs;
  __syncthreads();
  if (tid == 0)
    frobp[b] = wred[0] + wred[1] + wred[2] + wred[3];
}

// ---------------------------------------------------------------------------
// kfinal: fp64 reduce + scalar math.
// ---------------------------------------------------------------------------
__global__ void __launch_bounds__(256) kfinal(const double* __restrict__ rowp,
                                              const double* __restrict__ cssp,
                                              const int* __restrict__ cntp,
                                              const double* __restrict__ frobp,
                                              float* __restrict__ out) {
  __shared__ double red[256];
  const int tid = threadIdx.x;
  double lsum = rowp[tid] + rowp[tid + 256];
  double lcss = 0.0, lcnn = 0.0, lfr = 0.0;
  for (int c = tid; c < N_CLS; c += 256) {
    lcss += cssp[c];
    const double nc = (double)cntp[c];
    lcnn += nc * nc;
  }
  for (int c = tid; c < NBLK; c += 256) lfr += frobp[c];

  double vals[4] = {lsum, lcss, lcnn, lfr};
  double res[4];
  for (int v = 0; v < 4; ++v) {
    red[tid] = vals[v];
    __syncthreads();
    for (int s = 128; s; s >>= 1) {
      if (tid < s) red[tid] += red[tid + s];
      __syncthreads();
    }
    res[v] = red[0];
    __syncthreads();
  }
  if (tid == 0) {
    const double sumr = res[0], css = res[1], cnn = res[2], frob = res[3];
    const double S1 = 0.5 * (css - sumr);
    const double S2 = 0.5 * (cnn - (double)N_ROWS);
    const double S3 = frob;
    out[0] = (float)(-(S1 / (S2 * sqrt(S3))));
  }
}

extern "C" void kernel_launch(void* const* d_in, const int* in_sizes, int n_in,
                              void* d_out, int out_size, void* d_ws, size_t ws_size,
                              hipStream_t stream) {
  const float* A = (const float*)d_in[0];
  const int* target = (const int*)d_in[1];
  float* out = (float*)d_out;

  char* ws = (char*)d_ws;
  short*  Ab    = (short*)ws;                                   // 8,388,608 B
  double* rowp  = (double*)(ws + 8388608);                      // 512 doubles
  double* cssp  = (double*)(ws + 8388608 + 4096);               // 1000 doubles
  int*    cntp  = (int*)   (ws + 8388608 + 4096 + 8000);        // 1000 ints (pad 4096)
  double* frobp = (double*)(ws + 8388608 + 4096 + 8000 + 4096); // 528 doubles

  kprep<<<512 + N_CLS, 256, 0, stream>>>(A, target, Ab, rowp, cssp, cntp);
  kfrob<<<NBLK, 256, 0, stream>>>(Ab, frobp);
  kfinal<<<1, 256, 0, stream>>>(rowp, cssp, cntp, frobp, out);
}

// Round 11
// 46.945 us; speedup vs baseline: 1.2722x; 1.0167x over previous
//
#include <hip/hip_runtime.h>
#include <hip/hip_bf16.h>

// AlignmentLoss: loss = -(sum(tril(G,-1)*eq) / (sum(tril(eq,-1)) * ||tril(G,-1)||_F))
// with G = A A^T, A: 4096x1024 fp32, target: 4096 int32 (classes < 1000).
//
//   S1 = 0.5*(sum_c ||s_c||^2 - sum_i ||a_i||^2)   (exact fp32/fp64 path)
//   S2 = 0.5*(sum_c n_c^2 - N)
//   S3 = sum_{i>j} g_ij^2  -- lower-triangle tiles of G, bf16 MFMA, fused
//        masked Frobenius (no C materialization).
//   loss = -S1 / (S2 * sqrt(S3))
//
// R11 (structural): six scheduling/LDS/occupancy variants (R3-R10) were all
// neutral -> kfrob is staged-BYTE delivery bound (~8.4 TB/s on 270 MB).
// Fix: 256x256 tiles -> 136 blocks, staged bytes halve to 135 MB.
// 8 waves/block (2x4, 128x64 per wave, acc 8x4), BK=32, 64 KB LDS dbuf
// (carved pool), counted-vmcnt(4) pipeline, both-sides bank swizzle,
// bijective XCD swizzle (136 = 8*17).  kclass rides in the same launch as
// blocks 136..1135 (independent of Ab; hides under the delivery wall).

typedef __attribute__((ext_vector_type(8))) short short8;
typedef __attribute__((ext_vector_type(4))) float f32x4;

#define N_ROWS 4096
#define D_DIM  1024
#define N_CLS  1000
#define NTIL   136         // 16*(16+1)/2 lower-triangle 256^2 tiles
#define NK     32          // 1024 / BK,  BK = 32

__device__ __forceinline__ unsigned short f2bf(float f) {
  unsigned u = __float_as_uint(f);
  u += 0x7fffu + ((u >> 16) & 1u);   // round-to-nearest-even
  return (unsigned short)(u >> 16);
}

__device__ __forceinline__ void gload16(const short* g, const char* l) {
  __builtin_amdgcn_global_load_lds(
      (const __attribute__((address_space(1))) unsigned*)g,
      (__attribute__((address_space(3))) unsigned*)(void*)l, 16, 0, 0);
}

// ---------------------------------------------------------------------------
// kconv: A fp32 -> Ab bf16 + per-block fp64 partial of sum ||a_i||^2.
// 512 blocks x 256 thr (unchanged from R7-best).
// ---------------------------------------------------------------------------
__global__ void __launch_bounds__(256) kconv(const float* __restrict__ A,
                                             short* __restrict__ Ab,
                                             double* __restrict__ rowp) {
  __shared__ double wr2[4];
  const int tid = threadIdx.x, lane = tid & 63, w = tid >> 6;
  const int row0 = blockIdx.x * 8;
  double ls = 0.0;
#pragma unroll
  for (int rr = 0; rr < 2; ++rr) {
    const int i = row0 + w * 2 + rr;
    const float4* src = (const float4*)(A + (size_t)i * D_DIM);
    short4* dst = (short4*)(Ab + (size_t)i * D_DIM);
    float s = 0.f;
#pragma unroll
    for (int c = 0; c < 4; ++c) {
      const float4 v = src[lane + c * 64];
      s += v.x * v.x + v.y * v.y + v.z * v.z + v.w * v.w;
      short4 o;
      o.x = (short)f2bf(v.x); o.y = (short)f2bf(v.y);
      o.z = (short)f2bf(v.z); o.w = (short)f2bf(v.w);
      dst[lane + c * 64] = o;
    }
#pragma unroll
    for (int off = 32; off; off >>= 1) s += __shfl_down(s, off);
    if (lane == 0) ls += (double)s;
  }
  if (lane == 0) wr2[w] = ls;
  __syncthreads();
  if (tid == 0) rowp[blockIdx.x] = wr2[0] + wr2[1] + wr2[2] + wr2[3];
}

// ---------------------------------------------------------------------------
// kmain: blocks 0..135   = 256x256 gram tile, fused masked Frobenius
//        blocks 136..    = per-class sum-vector norm + count (reads A only)
// 512 threads.  Shared pool carved per branch (union -> 64.1 KB).
// ---------------------------------------------------------------------------
__global__ void __launch_bounds__(512, 2) kmain(const float* __restrict__ A,
                                                const int* __restrict__ target,
                                                const short* __restrict__ Ab,
                                                double* __restrict__ frobp,
                                                double* __restrict__ cssp,
                                                int* __restrict__ cntp) {
  __shared__ __align__(16) char smem[65600];
  const int tid = threadIdx.x, lane = tid & 63, w = tid >> 6;

  if (blockIdx.x < NTIL) {
    // ---------------- gram tile ----------------
    double* wredd = (double*)(smem + 65536);   // 8 doubles

    // bijective XCD swizzle: 136 = 8 * 17
    const int b = (blockIdx.x & 7) * 17 + (blockIdx.x >> 3);
    // decode lower-triangle pair: b = bi*(bi+1)/2 + bj, bj <= bi  (bi < 16)
    int bi = (int)((sqrtf(8.f * (float)b + 1.f) - 1.f) * 0.5f);
    while ((bi + 1) * (bi + 2) / 2 <= b) ++bi;
    while (bi * (bi + 1) / 2 > b) --bi;
    const int bj = b - bi * (bi + 1) / 2;
    const bool diag = (bi == bj);

    const short* Pa = Ab + (size_t)(bi * 256) * D_DIM;
    const short* Pb = Ab + (size_t)(bj * 256) * D_DIM;

    f32x4 acc[8][4];
#pragma unroll
    for (int m = 0; m < 8; ++m)
#pragma unroll
      for (int n = 0; n < 4; ++n) acc[m][n] = (f32x4){0.f, 0.f, 0.f, 0.f};

    const int wr = w >> 2, wc = w & 3;           // wave tile: 128 rows x 64 cols
    const int row16 = lane & 15, ck = lane >> 4;

    // staging: buffer = 256 rows x 32 cols shorts = 16 KB per matrix.
    // 512 thr x 16 B x 2 issues per matrix.  Global chunk pre-swizzled
    // (chunk ^= (row>>1)&3, invariant under +128 rows); LDS linear.
    const int sr = tid >> 2;                     // 0..127
    const int scS = (tid & 3) ^ ((sr >> 1) & 3);
    const size_t g0 = (size_t)sr * D_DIM + scS * 8;           // rows 0..127
    const size_t g1 = (size_t)(sr + 128) * D_DIM + scS * 8;   // rows 128..255
    const int l0 = w * 1024;                     // + issue*8192 (bytes)
    const int l1 = 8192 + w * 1024;

    // pool layout: As buf b at b*16384; Bs buf b at 32768 + b*16384
#define ASB(buf) (smem + (buf) * 16384)
#define BSB(buf) (smem + 32768 + (buf) * 16384)

#define STAGE(buf, k0)                                                      \
    do {                                                                    \
      gload16(Pa + g0 + (k0), ASB(buf) + l0);                               \
      gload16(Pa + g1 + (k0), ASB(buf) + l1);                               \
      gload16(Pb + g0 + (k0), BSB(buf) + l0);                               \
      gload16(Pb + g1 + (k0), BSB(buf) + l1);                               \
    } while (0)

#define SWZ(R) (((R) * 32) + ((ck ^ (((R) >> 1) & 3)) * 8))

#define COMPUTE(buf)                                                        \
    do {                                                                    \
      short8 af[8], bf[4];                                                  \
      _Pragma("unroll")                                                     \
      for (int m = 0; m < 8; ++m)                                           \
        af[m] = *(const short8*)((short*)ASB(buf) + SWZ(wr * 128 + m * 16 + row16)); \
      _Pragma("unroll")                                                     \
      for (int n = 0; n < 4; ++n)                                           \
        bf[n] = *(const short8*)((short*)BSB(buf) + SWZ(wc * 64 + n * 16 + row16)); \
      _Pragma("unroll")                                                     \
      for (int m = 0; m < 8; ++m)                                           \
        _Pragma("unroll")                                                   \
        for (int n = 0; n < 4; ++n)                                         \
          acc[m][n] = __builtin_amdgcn_mfma_f32_16x16x32_bf16(af[m], bf[n], \
                                                              acc[m][n], 0, 0, 0); \
    } while (0)

    STAGE(0, 0);                       // prologue: tile 0 in flight
    int cur = 0;
#pragma unroll 1
    for (int t = 0; t < NK - 1; ++t) {
      STAGE(cur ^ 1, (t + 1) * 32);    // issue next tile (4 loads/thread)
      asm volatile("s_waitcnt vmcnt(4)" ::: "memory");   // tile t resident
      __builtin_amdgcn_sched_barrier(0);
      __builtin_amdgcn_s_barrier();
      __builtin_amdgcn_sched_barrier(0);
      COMPUTE(cur);
      asm volatile("s_waitcnt lgkmcnt(0)" ::: "memory"); // ds_reads retired
      __builtin_amdgcn_sched_barrier(0);
      __builtin_amdgcn_s_barrier();    // buf cur free for overwrite
      __builtin_amdgcn_sched_barrier(0);
      cur ^= 1;
    }
    asm volatile("s_waitcnt vmcnt(0)" ::: "memory");     // last tile resident
    __builtin_amdgcn_sched_barrier(0);
    __builtin_amdgcn_s_barrier();
    __builtin_amdgcn_sched_barrier(0);
    COMPUTE(cur);
#undef STAGE
#undef COMPUTE
#undef SWZ
#undef ASB
#undef BSB

    float fs = 0.f;
    if (!diag) {
#pragma unroll
      for (int m = 0; m < 8; ++m)
#pragma unroll
        for (int n = 0; n < 4; ++n)
#pragma unroll
          for (int q = 0; q < 4; ++q) fs += acc[m][n][q] * acc[m][n][q];
    } else {
      const int rbase = (lane >> 4) * 4, cbase = lane & 15;
#pragma unroll
      for (int m = 0; m < 8; ++m)
#pragma unroll
        for (int n = 0; n < 4; ++n)
#pragma unroll
          for (int q = 0; q < 4; ++q) {
            const int rl = wr * 128 + m * 16 + rbase + q;
            const int cl = wc * 64 + n * 16 + cbase;
            if (rl > cl) fs += acc[m][n][q] * acc[m][n][q];
          }
    }
#pragma unroll
    for (int off = 32; off; off >>= 1) fs += __shfl_down(fs, off);
    if (lane == 0) wredd[w] = (double)fs;
    __syncthreads();
    if (tid == 0) {
      double t = 0.0;
#pragma unroll
      for (int i = 0; i < 8; ++i) t += wredd[i];
      frobp[b] = t;
    }
  } else {
    // ---------------- per-class reduction (512 thr, 2 dims/thread) --------
    int* list = (int*)smem;                      // 4096 ints = 16 KB
    int* lcnt = (int*)(smem + 16384);
    float* wredf = (float*)(smem + 16400);       // 8 floats
    const int c = blockIdx.x - NTIL;
    if (c >= N_CLS) return;
    if (tid == 0) *lcnt = 0;
    __syncthreads();
    for (int j = tid; j < N_ROWS; j += 512)
      if (target[j] == c) { int p = atomicAdd(lcnt, 1); list[p] = j; }
    __syncthreads();
    const int n = *lcnt;
    float2 acc = make_float2(0.f, 0.f);
    for (int m = 0; m < n; ++m) {
      const float2 v = *(const float2*)(A + (size_t)list[m] * D_DIM + tid * 2);
      acc.x += v.x; acc.y += v.y;
    }
    float s = acc.x * acc.x + acc.y * acc.y;
#pragma unroll
    for (int off = 32; off; off >>= 1) s += __shfl_down(s, off);
    if (lane == 0) wredf[w] = s;
    __syncthreads();
    if (tid == 0) {
      float t = 0.f;
#pragma unroll
      for (int i = 0; i < 8; ++i) t += wredf[i];
      cssp[c] = (double)t;
      cntp[c] = n;
    }
  }
}

// ---------------------------------------------------------------------------
// kfinal: fp64 reduce + scalar math.
// ---------------------------------------------------------------------------
__global__ void __launch_bounds__(256) kfinal(const double* __restrict__ rowp,
                                              const double* __restrict__ cssp,
                                              const int* __restrict__ cntp,
                                              const double* __restrict__ frobp,
                                              float* __restrict__ out) {
  __shared__ double red[256];
  const int tid = threadIdx.x;
  double lsum = rowp[tid] + rowp[tid + 256];
  double lcss = 0.0, lcnn = 0.0, lfr = 0.0;
  for (int c = tid; c < N_CLS; c += 256) {
    lcss += cssp[c];
    const double nc = (double)cntp[c];
    lcnn += nc * nc;
  }
  if (tid < NTIL) lfr = frobp[tid];

  double vals[4] = {lsum, lcss, lcnn, lfr};
  double res[4];
  for (int v = 0; v < 4; ++v) {
    red[tid] = vals[v];
    __syncthreads();
    for (int s = 128; s; s >>= 1) {
      if (tid < s) red[tid] += red[tid + s];
      __syncthreads();
    }
    res[v] = red[0];
    __syncthreads();
  }
  if (tid == 0) {
    const double sumr = res[0], css = res[1], cnn = res[2], frob = res[3];
    const double S1 = 0.5 * (css - sumr);
    const double S2 = 0.5 * (cnn - (double)N_ROWS);
    const double S3 = frob;
    out[0] = (float)(-(S1 / (S2 * sqrt(S3))));
  }
}

extern "C" void kernel_launch(void* const* d_in, const int* in_sizes, int n_in,
                              void* d_out, int out_size, void* d_ws, size_t ws_size,
                              hipStream_t stream) {
  const float* A = (const float*)d_in[0];
  const int* target = (const int*)d_in[1];
  float* out = (float*)d_out;

  char* ws = (char*)d_ws;
  short*  Ab    = (short*)ws;                                   // 8,388,608 B
  double* rowp  = (double*)(ws + 8388608);                      // 512 doubles
  double* cssp  = (double*)(ws + 8388608 + 4096);               // 1000 doubles
  int*    cntp  = (int*)   (ws + 8388608 + 4096 + 8000);        // 1000 ints (pad 4096)
  double* frobp = (double*)(ws + 8388608 + 4096 + 8000 + 4096); // 136 doubles

  kconv<<<512, 256, 0, stream>>>(A, Ab, rowp);
  kmain<<<NTIL + N_CLS, 512, 0, stream>>>(A, target, Ab, frobp, cssp, cntp);
  kfinal<<<1, 256, 0, stream>>>(rowp, cssp, cntp, frobp, out);
}

// Round 12
// 45.479 us; speedup vs baseline: 1.3132x; 1.0322x over previous
//
#include <hip/hip_runtime.h>
#include <hip/hip_bf16.h>

// AlignmentLoss: loss = -(sum(tril(G,-1)*eq) / (sum(tril(eq,-1)) * ||tril(G,-1)||_F))
// with G = A A^T, A: 4096x1024 fp32, target: 4096 int32 (classes < 1000).
//
//   S1 = 0.5*(sum_c ||s_c||^2 - sum_i ||a_i||^2)   (exact fp32/fp64 path)
//   S2 = 0.5*(sum_c n_c^2 - N)
//   S3 = sum_{i>j} g_ij^2  -- lower-triangle 256x256 tiles, bf16 MFMA,
//        fused masked Frobenius.
//   loss = -S1 / (S2 * sqrt(S3))
//
// R12 (structural): 8-phase schedule (m201 template) on the 256^2 gram.
// 136 blocks x 512 thr (8 waves 2x4), BK=64, 128 KB LDS (2 bufs x {A,B}),
// per K-tile 4 quadrant-phases of 16 MFMA between raw s_barriers, stages
// spread 2/phase into the other buffer >=2 phases ahead, vmcnt(0) only at
// K-tile boundaries, setprio around MFMA.  Swizzle/numerics unchanged.

typedef __attribute__((ext_vector_type(8))) short short8;
typedef __attribute__((ext_vector_type(4))) float f32x4;

#define N_ROWS 4096
#define D_DIM  1024
#define N_CLS  1000
#define NTIL   136         // 16*17/2 lower-triangle 256^2 tiles

__device__ __forceinline__ unsigned short f2bf(float f) {
  unsigned u = __float_as_uint(f);
  u += 0x7fffu + ((u >> 16) & 1u);   // round-to-nearest-even
  return (unsigned short)(u >> 16);
}

__device__ __forceinline__ void gload16(const short* g, const char* l) {
  __builtin_amdgcn_global_load_lds(
      (const __attribute__((address_space(1))) unsigned*)g,
      (__attribute__((address_space(3))) unsigned*)(void*)l, 16, 0, 0);
}

// ---------------------------------------------------------------------------
// kconv: A fp32 -> Ab bf16 + per-block fp64 partial of sum ||a_i||^2.
// ---------------------------------------------------------------------------
__global__ void __launch_bounds__(256) kconv(const float* __restrict__ A,
                                             short* __restrict__ Ab,
                                             double* __restrict__ rowp) {
  __shared__ double wr2[4];
  const int tid = threadIdx.x, lane = tid & 63, w = tid >> 6;
  const int row0 = blockIdx.x * 8;
  double ls = 0.0;
#pragma unroll
  for (int rr = 0; rr < 2; ++rr) {
    const int i = row0 + w * 2 + rr;
    const float4* src = (const float4*)(A + (size_t)i * D_DIM);
    short4* dst = (short4*)(Ab + (size_t)i * D_DIM);
    float s = 0.f;
#pragma unroll
    for (int c = 0; c < 4; ++c) {
      const float4 v = src[lane + c * 64];
      s += v.x * v.x + v.y * v.y + v.z * v.z + v.w * v.w;
      short4 o;
      o.x = (short)f2bf(v.x); o.y = (short)f2bf(v.y);
      o.z = (short)f2bf(v.z); o.w = (short)f2bf(v.w);
      dst[lane + c * 64] = o;
    }
#pragma unroll
    for (int off = 32; off; off >>= 1) s += __shfl_down(s, off);
    if (lane == 0) ls += (double)s;
  }
  if (lane == 0) wr2[w] = ls;
  __syncthreads();
  if (tid == 0) rowp[blockIdx.x] = wr2[0] + wr2[1] + wr2[2] + wr2[3];
}

// ---------------------------------------------------------------------------
// kmain: blocks 0..135 = 256^2 gram tile (8-phase); blocks 136.. = class.
// ---------------------------------------------------------------------------
__global__ void __launch_bounds__(512, 2) kmain(const float* __restrict__ A,
                                                const int* __restrict__ target,
                                                const short* __restrict__ Ab,
                                                double* __restrict__ frobp,
                                                double* __restrict__ cssp,
                                                int* __restrict__ cntp) {
  __shared__ __align__(16) char smem[131072];   // 128 KB pool
  const int tid = threadIdx.x, lane = tid & 63, w = tid >> 6;

  if (blockIdx.x < NTIL) {
    // ---------------- gram tile, 8-phase ----------------
    // bijective XCD swizzle: 136 = 8 * 17
    const int b = (blockIdx.x & 7) * 17 + (blockIdx.x >> 3);
    int bi = (int)((sqrtf(8.f * (float)b + 1.f) - 1.f) * 0.5f);
    while ((bi + 1) * (bi + 2) / 2 <= b) ++bi;
    while (bi * (bi + 1) / 2 > b) --bi;
    const int bj = b - bi * (bi + 1) / 2;
    const bool diag = (bi == bj);

    const short* Pa = Ab + (size_t)(bi * 256) * D_DIM;
    const short* Pb = Ab + (size_t)(bj * 256) * D_DIM;

    // LDS: per buf per matrix 32 KB = [2 ksub][256 rows][64 B]
    short* As0 = (short*)smem;
    short* As1 = (short*)(smem + 32768);
    short* Bs0 = (short*)(smem + 65536);
    short* Bs1 = (short*)(smem + 98304);

    f32x4 acc[8][4];
#pragma unroll
    for (int m = 0; m < 8; ++m)
#pragma unroll
      for (int n = 0; n < 4; ++n) acc[m][n] = (f32x4){0.f, 0.f, 0.f, 0.f};

    const int wm = w >> 2, wn = w & 3;       // wave: rows wm*128, cols wn*64
    const int row16 = lane & 15, ck = lane >> 4;

    // staging: unit = (matrix, half h, K-tile kt): 2 gload16/thread (16 KB)
    const int sr = tid >> 2;                 // 0..127
    const int scS = (tid & 3) ^ ((sr >> 1) & 3);

#define STAGEU(P, BUF, h, kt)                                               \
    do {                                                                    \
      const short* _g = (P) + ((size_t)((h) * 128 + sr)) * D_DIM + (kt) * 64 + scS * 8; \
      gload16(_g,      (const char*)(BUF) + (h) * 8192 + w * 1024);         \
      gload16(_g + 32, (const char*)(BUF) + 16384 + (h) * 8192 + w * 1024); \
    } while (0)

#define RD_A(BUF, MH)                                                       \
    _Pragma("unroll") for (int ks = 0; ks < 2; ++ks)                        \
    _Pragma("unroll") for (int m = 0; m < 4; ++m) {                         \
      const int R = wm * 128 + ((MH) * 4 + m) * 16 + row16;                 \
      a[ks][m] = *(const short8*)((const char*)(BUF) + ks * 16384 + R * 64  \
                                  + ((ck ^ ((R >> 1) & 3)) << 4));          \
    }
#define RD_B(DST, BUF, NH)                                                  \
    _Pragma("unroll") for (int ks = 0; ks < 2; ++ks)                        \
    _Pragma("unroll") for (int n = 0; n < 2; ++n) {                         \
      const int R = wn * 64 + ((NH) * 2 + n) * 16 + row16;                  \
      DST[ks][n] = *(const short8*)((const char*)(BUF) + ks * 16384 + R * 64\
                                    + ((ck ^ ((R >> 1) & 3)) << 4));        \
    }
#define PH_MFMA(MO, NO, BB)                                                 \
    __builtin_amdgcn_s_setprio(1);                                          \
    _Pragma("unroll") for (int ks = 0; ks < 2; ++ks)                        \
    _Pragma("unroll") for (int m = 0; m < 4; ++m)                           \
    _Pragma("unroll") for (int n = 0; n < 2; ++n)                           \
      acc[(MO) + m][(NO) + n] = __builtin_amdgcn_mfma_f32_16x16x32_bf16(    \
          a[ks][m], BB[ks][n], acc[(MO) + m][(NO) + n], 0, 0, 0);           \
    __builtin_amdgcn_s_setprio(0);
#define BAR __builtin_amdgcn_s_barrier()
#define VM0 asm volatile("s_waitcnt vmcnt(0)" ::: "memory")

    // prologue: K-tile 0 -> buf0
    STAGEU(Pa, As0, 0, 0); STAGEU(Pa, As0, 1, 0);
    STAGEU(Pb, Bs0, 0, 0); STAGEU(Pb, Bs0, 1, 0);
    VM0;
    BAR;

#pragma unroll 1
    for (int it = 0; it < 8; ++it) {
      const int t1 = 2 * it + 1, t2 = 2 * it + 2;
      short8 a[2][4], bq0[2][2], b[2][2];
      // ---- ph1: t0 q0 (buf0) ; stage A of t1 -> buf1
      RD_A(As0, 0); RD_B(bq0, Bs0, 0);
      STAGEU(Pa, As1, 0, t1); STAGEU(Pa, As1, 1, t1);
      BAR;
      PH_MFMA(0, 0, bq0);
      BAR;
      // ---- ph2: q1 ; stage B of t1 -> buf1
      RD_B(b, Bs0, 1);
      STAGEU(Pb, Bs1, 0, t1); STAGEU(Pb, Bs1, 1, t1);
      BAR;
      PH_MFMA(0, 2, b);
      BAR;
      // ---- ph3: q2
      RD_A(As0, 1);
      BAR;
      PH_MFMA(4, 2, b);
      BAR;
      // ---- ph4: q3 (no reads/stages)
      PH_MFMA(4, 0, bq0);
      BAR;
      VM0;                 // t1's units (staged ph1-2) resident everywhere
      BAR;
      // ---- ph5: t1 q0 (buf1) ; stage A of t2 -> buf0 (freed after ph4)
      RD_A(As1, 0); RD_B(bq0, Bs1, 0);
      if (it < 7) { STAGEU(Pa, As0, 0, t2); STAGEU(Pa, As0, 1, t2); }
      BAR;
      PH_MFMA(0, 0, bq0);
      BAR;
      // ---- ph6: q1 ; stage B of t2 -> buf0
      RD_B(b, Bs1, 1);
      if (it < 7) { STAGEU(Pb, Bs0, 0, t2); STAGEU(Pb, Bs0, 1, t2); }
      BAR;
      PH_MFMA(0, 2, b);
      BAR;
      // ---- ph7: q2
      RD_A(As1, 1);
      BAR;
      PH_MFMA(4, 2, b);
      BAR;
      // ---- ph8: q3
      PH_MFMA(4, 0, bq0);
      BAR;
      VM0;                 // t2's units (staged ph5-6) resident
      BAR;
    }
#undef STAGEU
#undef RD_A
#undef RD_B
#undef PH_MFMA
#undef BAR
#undef VM0

    // epilogue: masked Frobenius
    float fs = 0.f;
    if (!diag) {
#pragma unroll
      for (int m = 0; m < 8; ++m)
#pragma unroll
        for (int n = 0; n < 4; ++n)
#pragma unroll
          for (int q = 0; q < 4; ++q) fs += acc[m][n][q] * acc[m][n][q];
    } else {
      const int rbase = (lane >> 4) * 4, cbase = lane & 15;
#pragma unroll
      for (int m = 0; m < 8; ++m)
#pragma unroll
        for (int n = 0; n < 4; ++n)
#pragma unroll
          for (int q = 0; q < 4; ++q) {
            const int rl = wm * 128 + m * 16 + rbase + q;
            const int cl = wn * 64 + n * 16 + cbase;
            if (rl > cl) fs += acc[m][n][q] * acc[m][n][q];
          }
    }
#pragma unroll
    for (int off = 32; off; off >>= 1) fs += __shfl_down(fs, off);
    double* wredd = (double*)smem;       // LDS free after the loop
    if (lane == 0) wredd[w] = (double)fs;
    __syncthreads();
    if (tid == 0) {
      double t = 0.0;
#pragma unroll
      for (int i = 0; i < 8; ++i) t += wredd[i];
      frobp[b] = t;
    }
  } else {
    // ---------------- per-class reduction ----------------
    int* list = (int*)smem;                      // 16 KB
    int* lcnt = (int*)(smem + 16384);
    float* wredf = (float*)(smem + 16400);       // 8 floats
    const int c = blockIdx.x - NTIL;
    if (c >= N_CLS) return;
    if (tid == 0) *lcnt = 0;
    __syncthreads();
    for (int j = tid; j < N_ROWS; j += 512)
      if (target[j] == c) { int p = atomicAdd(lcnt, 1); list[p] = j; }
    __syncthreads();
    const int n = *lcnt;
    float2 acc = make_float2(0.f, 0.f);
    for (int m = 0; m < n; ++m) {
      const float2 v = *(const float2*)(A + (size_t)list[m] * D_DIM + tid * 2);
      acc.x += v.x; acc.y += v.y;
    }
    float s = acc.x * acc.x + acc.y * acc.y;
#pragma unroll
    for (int off = 32; off; off >>= 1) s += __shfl_down(s, off);
    if (lane == 0) wredf[w] = s;
    __syncthreads();
    if (tid == 0) {
      float t = 0.f;
#pragma unroll
      for (int i = 0; i < 8; ++i) t += wredf[i];
      cssp[c] = (double)t;
      cntp[c] = n;
    }
  }
}

// ---------------------------------------------------------------------------
// kfinal: fp64 reduce + scalar math.
// ---------------------------------------------------------------------------
__global__ void __launch_bounds__(256) kfinal(const double* __restrict__ rowp,
                                              const double* __restrict__ cssp,
                                              const int* __restrict__ cntp,
                                              const double* __restrict__ frobp,
                                              float* __restrict__ out) {
  __shared__ double red[256];
  const int tid = threadIdx.x;
  double lsum = rowp[tid] + rowp[tid + 256];
  double lcss = 0.0, lcnn = 0.0, lfr = 0.0;
  for (int c = tid; c < N_CLS; c += 256) {
    lcss += cssp[c];
    const double nc = (double)cntp[c];
    lcnn += nc * nc;
  }
  if (tid < NTIL) lfr = frobp[tid];

  double vals[4] = {lsum, lcss, lcnn, lfr};
  double res[4];
  for (int v = 0; v < 4; ++v) {
    red[tid] = vals[v];
    __syncthreads();
    for (int s = 128; s; s >>= 1) {
      if (tid < s) red[tid] += red[tid + s];
      __syncthreads();
    }
    res[v] = red[0];
    __syncthreads();
  }
  if (tid == 0) {
    const double sumr = res[0], css = res[1], cnn = res[2], frob = res[3];
    const double S1 = 0.5 * (css - sumr);
    const double S2 = 0.5 * (cnn - (double)N_ROWS);
    const double S3 = frob;
    out[0] = (float)(-(S1 / (S2 * sqrt(S3))));
  }
}

extern "C" void kernel_launch(void* const* d_in, const int* in_sizes, int n_in,
                              void* d_out, int out_size, void* d_ws, size_t ws_size,
                              hipStream_t stream) {
  const float* A = (const float*)d_in[0];
  const int* target = (const int*)d_in[1];
  float* out = (float*)d_out;

  char* ws = (char*)d_ws;
  short*  Ab    = (short*)ws;                                   // 8,388,608 B
  double* rowp  = (double*)(ws + 8388608);                      // 512 doubles
  double* cssp  = (double*)(ws + 8388608 + 4096);               // 1000 doubles
  int*    cntp  = (int*)   (ws + 8388608 + 4096 + 8000);        // 1000 ints (pad 4096)
  double* frobp = (double*)(ws + 8388608 + 4096 + 8000 + 4096); // 136 doubles

  kconv<<<512, 256, 0, stream>>>(A, Ab, rowp);
  kmain<<<NTIL + N_CLS, 512, 0, stream>>>(A, target, Ab, frobp, cssp, cntp);
  kfinal<<<1, 256, 0, stream>>>(rowp, cssp, cntp, frobp, out);
}